// Round 4
// baseline (266.097 us; speedup 1.0000x reference)
//
#include <hip/hip_runtime.h>
#include <math.h>

#define NSRC 50000
#define NTGT 50000
#define NTOT 100000
#define NEDGE 800000
#define DIM 128
#define SCAN_BLK 512    // elements per scan block
#define SCAN_NB 98      // ceil(50000/512)

typedef __attribute__((ext_vector_type(8))) short short8;
typedef __attribute__((ext_vector_type(4))) float float4v;

__device__ __forceinline__ unsigned short f2bf(float f) {
    unsigned u = __float_as_uint(f);
    unsigned r = (u + 0x7FFFu + ((u >> 16) & 1u)) >> 16;  // RNE
    return (unsigned short)r;
}
__device__ __forceinline__ float bf2f(unsigned us) {
    return __uint_as_float(us << 16);
}

// ---------------- prep: zero counters + W -> Wt (bf16, transposed) --------
__global__ void k_prep(const float* __restrict__ W, unsigned short* __restrict__ Wt,
                       int* __restrict__ cntcur) {
    int i = blockIdx.x * blockDim.x + threadIdx.x;
    if (i < 2 * NTGT) cntcur[i] = 0;
    if (i < DIM * DIM) {
        int k = i >> 7, n = i & 127;
        Wt[n * DIM + k] = f2bf(W[i]);
    }
}

// ---------------- histogram of targets ----------------
__global__ void k_hist(const int* __restrict__ col, int* __restrict__ cnt) {
    int e = blockIdx.x * blockDim.x + threadIdx.x;
    if (e < NEDGE) atomicAdd(&cnt[col[e]], 1);
}

// ---------------- scan (block-local) + top-level block sums ----------------
__global__ __launch_bounds__(SCAN_BLK) void k_scan_block(const int* __restrict__ cnt,
                                                         int* __restrict__ off,
                                                         int* __restrict__ bsum) {
    __shared__ int A[SCAN_BLK], B[SCAN_BLK];
    int tid = threadIdx.x;
    int i = blockIdx.x * SCAN_BLK + tid;
    int v = (i < NTGT) ? cnt[i] : 0;
    A[tid] = v;
    int* src = A; int* dst = B;
    for (int d = 1; d < SCAN_BLK; d <<= 1) {
        __syncthreads();
        dst[tid] = src[tid] + ((tid >= d) ? src[tid - d] : 0);
        int* t = src; src = dst; dst = t;
    }
    __syncthreads();
    if (i < NTGT) off[i] = src[tid] - v;  // block-local exclusive
    if (tid == SCAN_BLK - 1) bsum[blockIdx.x] = src[tid];
}

__global__ __launch_bounds__(128) void k_scan_top(int* __restrict__ bsum,
                                                  int* __restrict__ bscan) {
    __shared__ int A[128], B[128];
    int tid = threadIdx.x;
    int v = (tid < SCAN_NB) ? bsum[tid] : 0;
    A[tid] = v;
    int* src = A; int* dst = B;
    for (int d = 1; d < 128; d <<= 1) {
        __syncthreads();
        dst[tid] = src[tid] + ((tid >= d) ? src[tid - d] : 0);
        int* t = src; src = dst; dst = t;
    }
    __syncthreads();
    if (tid < SCAN_NB) bscan[tid] = src[tid] - v;
}

// ---------------- bucket edges by target (bscan folded in) ----------------
__global__ void k_build(const int* __restrict__ row, const int* __restrict__ col,
                        const int* __restrict__ off, const int* __restrict__ bscan,
                        int* __restrict__ cursor, int* __restrict__ csr) {
    int e = blockIdx.x * blockDim.x + threadIdx.x;
    if (e < NEDGE) {
        int c = col[e];
        int pos = off[c] + bscan[c >> 9] + atomicAdd(&cursor[c], 1);
        csr[pos] = row[e];
    }
}

// ---------------- h = x @ W via bf16 MFMA; Wt read direct from global -----
// block = 256 thr (4 waves), 64 rows/block. Wave w -> rows base+w*16..+15.
// 8 n-tiles of 16 cols; K=128 in 4 MFMA steps of 32.
__global__ __launch_bounds__(256) void k_gemm(const float* __restrict__ xsrc,
                                              const float* __restrict__ xtgt,
                                              const unsigned short* __restrict__ Wt,
                                              unsigned short* __restrict__ h,
                                              float* __restrict__ out) {
    __shared__ unsigned short Hs[64 * 128];  // epilogue staging only (16 KB)

    const int tid = threadIdx.x;
    const int wave = tid >> 6, lane = tid & 63;
    const int nl = lane & 15, quad = lane >> 4;
    const int base = blockIdx.x * 64;

    int m = base + wave * 16 + nl;
    int mc = (m < NTOT) ? m : (NTOT - 1);  // clamp tail loads
    const float* xrow = (mc < NSRC) ? (xsrc + (size_t)mc * DIM)
                                    : (xtgt + (size_t)(mc - NSRC) * DIM);

    float4v acc[8];
#pragma unroll
    for (int t = 0; t < 8; ++t) acc[t] = (float4v){0.f, 0.f, 0.f, 0.f};

#pragma unroll
    for (int s = 0; s < 4; ++s) {
        int k0 = s * 32 + quad * 8;
        float4 a0 = *(const float4*)(xrow + k0);
        float4 a1 = *(const float4*)(xrow + k0 + 4);
        short8 af;
        af[0] = (short)f2bf(a0.x); af[1] = (short)f2bf(a0.y);
        af[2] = (short)f2bf(a0.z); af[3] = (short)f2bf(a0.w);
        af[4] = (short)f2bf(a1.x); af[5] = (short)f2bf(a1.y);
        af[6] = (short)f2bf(a1.z); af[7] = (short)f2bf(a1.w);
#pragma unroll
        for (int t = 0; t < 8; ++t) {
            short8 bf = *(const short8*)(Wt + (size_t)(t * 16 + nl) * DIM + k0);
            acc[t] = __builtin_amdgcn_mfma_f32_16x16x32_bf16(af, bf, acc[t], 0, 0, 0);
        }
    }

    // C/D layout: col = lane&15 (within n-tile), row = quad*4 + reg
#pragma unroll
    for (int t = 0; t < 8; ++t)
#pragma unroll
        for (int r = 0; r < 4; ++r)
            Hs[(wave * 16 + quad * 4 + r) * 128 + t * 16 + nl] = f2bf(acc[t][r]);
    __syncthreads();

    // coalesced readout: each thread 4 chunks of 8 bf16
#pragma unroll
    for (int j = 0; j < 4; ++j) {
        int off_us = tid * 8 + j * 2048;  // ushort index into Hs
        int g = base + (off_us >> 7);
        int colc = off_us & 127;
        if (g < NTOT) {
            uint4 v = *(const uint4*)&Hs[off_us];
            *(uint4*)(h + (size_t)g * DIM + colc) = v;
            if (g < NSRC) {  // source nodes: deg=1 -> out = relu(h)
                unsigned pk[4] = {v.x, v.y, v.z, v.w};
                float4 o0, o1;
                o0.x = fmaxf(bf2f(pk[0] & 0xffff), 0.f);
                o0.y = fmaxf(bf2f(pk[0] >> 16), 0.f);
                o0.z = fmaxf(bf2f(pk[1] & 0xffff), 0.f);
                o0.w = fmaxf(bf2f(pk[1] >> 16), 0.f);
                o1.x = fmaxf(bf2f(pk[2] & 0xffff), 0.f);
                o1.y = fmaxf(bf2f(pk[2] >> 16), 0.f);
                o1.z = fmaxf(bf2f(pk[3] & 0xffff), 0.f);
                o1.w = fmaxf(bf2f(pk[3] >> 16), 0.f);
                float* op = out + (size_t)g * DIM + colc;
                *(float4*)op = o0;
                *(float4*)(op + 4) = o1;
            }
        }
    }
}

// ---------------- per-target gather-reduce (bf16 h, 2 edges/iter) ---------
// one wave per target; half-wave (32 lanes) per edge, uint2 (4 bf16)/lane
__global__ __launch_bounds__(256) void k_agg(const int* __restrict__ off,
                                             const int* __restrict__ cnt,
                                             const int* __restrict__ bscan,
                                             const int* __restrict__ csr,
                                             const unsigned short* __restrict__ h,
                                             float* __restrict__ out) {
    int w = threadIdx.x >> 6;
    int lane = threadIdx.x & 63;
    int c = blockIdx.x * 4 + w;
    if (c >= NTGT) return;

    int s0 = off[c] + bscan[c >> 9];
    int n = cnt[c];
    int half = lane >> 5;   // 0: even edges, 1: odd edges
    int hl = lane & 31;     // covers cols 4*hl .. 4*hl+3

    float4 sum = make_float4(0.f, 0.f, 0.f, 0.f);
    int j = 0;
    while (j < n) {
        int nb = (n - j < 64) ? (n - j) : 64;
        int v = (lane < nb) ? csr[s0 + j + lane] : 0;
        int npair = nb & ~1;
        int kk = 0;
#pragma unroll 8
        for (; kk < npair; kk += 2) {
            int r = __shfl(v, kk + half, 64);
            uint2 d = *(const uint2*)(h + (size_t)r * DIM + hl * 4);
            sum.x += bf2f(d.x & 0xffff); sum.y += bf2f(d.x >> 16);
            sum.z += bf2f(d.y & 0xffff); sum.w += bf2f(d.y >> 16);
        }
        if (kk < nb) {  // odd leftover: half 0 only
            int r = __shfl(v, kk, 64);
            if (half == 0) {
                uint2 d = *(const uint2*)(h + (size_t)r * DIM + hl * 4);
                sum.x += bf2f(d.x & 0xffff); sum.y += bf2f(d.x >> 16);
                sum.z += bf2f(d.y & 0xffff); sum.w += bf2f(d.y >> 16);
            }
        }
        j += nb;
    }

    // combine halves: lane l (<32) needs + lane l+32
    float4 tot;
    tot.x = sum.x + __shfl(sum.x, lane ^ 32, 64);
    tot.y = sum.y + __shfl(sum.y, lane ^ 32, 64);
    tot.z = sum.z + __shfl(sum.z, lane ^ 32, 64);
    tot.w = sum.w + __shfl(sum.w, lane ^ 32, 64);

    if (half == 0) {
        float di = rsqrtf(1.0f + (float)n);
        float dd = di * di;
        uint2 dh = *(const uint2*)(h + (size_t)(NSRC + c) * DIM + hl * 4);
        float4 o;
        o.x = fmaxf(di * tot.x + dd * bf2f(dh.x & 0xffff), 0.f);
        o.y = fmaxf(di * tot.y + dd * bf2f(dh.x >> 16), 0.f);
        o.z = fmaxf(di * tot.z + dd * bf2f(dh.y & 0xffff), 0.f);
        o.w = fmaxf(di * tot.w + dd * bf2f(dh.y >> 16), 0.f);
        *(float4*)(out + (size_t)(NSRC + c) * DIM + hl * 4) = o;
    }
}

extern "C" void kernel_launch(void* const* d_in, const int* in_sizes, int n_in,
                              void* d_out, int out_size, void* d_ws, size_t ws_size,
                              hipStream_t stream) {
    const int* ei     = (const int*)d_in[0];    // [2, E] int32
    const float* xsrc = (const float*)d_in[1];  // [NSRC, 128]
    const float* xtgt = (const float*)d_in[2];  // [NTGT, 128]
    const float* W    = (const float*)d_in[3];  // [128, 128]
    float* out = (float*)d_out;                 // [NTOT, 128]

    const int* row = ei;
    const int* col = ei + NEDGE;

    char* ws = (char*)d_ws;
    unsigned short* h  = (unsigned short*)ws;  ws += (size_t)NTOT * DIM * 2;  // 25.6 MB
    unsigned short* Wt = (unsigned short*)ws;  ws += DIM * DIM * 2;           // 32 KB
    int* cnt    = (int*)ws;                    ws += NTGT * 4;
    int* cursor = (int*)ws;                    ws += NTGT * 4;
    int* off    = (int*)ws;                    ws += NTGT * 4;
    int* bsum   = (int*)ws;                    ws += 512;
    int* bscan  = (int*)ws;                    ws += 512;
    int* csr    = (int*)ws;                    ws += (size_t)NEDGE * 4;       // 3.2 MB

    k_prep<<<(2 * NTGT + 255) / 256, 256, 0, stream>>>(W, Wt, cnt);  // cnt+cursor adjacent
    k_hist<<<(NEDGE + 255) / 256, 256, 0, stream>>>(col, cnt);
    k_scan_block<<<SCAN_NB, SCAN_BLK, 0, stream>>>(cnt, off, bsum);
    k_scan_top<<<1, 128, 0, stream>>>(bsum, bscan);
    k_build<<<(NEDGE + 255) / 256, 256, 0, stream>>>(row, col, off, bscan, cursor, csr);
    k_gemm<<<(NTOT + 63) / 64, 256, 0, stream>>>(xsrc, xtgt, Wt, h, out);
    k_agg<<<(NTGT + 3) / 4, 256, 0, stream>>>(off, cnt, bscan, csr, h, out);
}

// Round 5
// 248.727 us; speedup vs baseline: 1.0698x; 1.0698x over previous
//
#include <hip/hip_runtime.h>
#include <math.h>

#define NSRC 50000
#define NTGT 50000
#define NTOT 100000
#define NEDGE 800000
#define DIM 128
#define SCAN_BLK 512    // elements per scan block
#define SCAN_NB 98      // ceil(50000/512)
#define WPAD 136        // Wt LDS row pitch (ushorts): 2-way bank alias = free
#define CHUNKS_PER_BLK 2
#define GEMM_GRID 782   // ceil(1563 / 2)

typedef __attribute__((ext_vector_type(8))) short short8;
typedef __attribute__((ext_vector_type(4))) float float4v;

__device__ __forceinline__ unsigned short f2bf(float f) {
    unsigned u = __float_as_uint(f);
    unsigned r = (u + 0x7FFFu + ((u >> 16) & 1u)) >> 16;  // RNE
    return (unsigned short)r;
}
__device__ __forceinline__ float bf2f(unsigned us) {
    return __uint_as_float(us << 16);
}

// ---------------- prep: zero cnt + W -> Wt (bf16, transposed) --------
__global__ void k_prep(const float* __restrict__ W, unsigned short* __restrict__ Wt,
                       int* __restrict__ cnt) {
    int i = blockIdx.x * blockDim.x + threadIdx.x;
    if (i < NTGT) cnt[i] = 0;
    if (i < DIM * DIM) {
        int k = i >> 7, n = i & 127;
        Wt[n * DIM + k] = f2bf(W[i]);
    }
}

// ---------------- histogram of targets ----------------
__global__ void k_hist(const int* __restrict__ col, int* __restrict__ cnt) {
    int e = blockIdx.x * blockDim.x + threadIdx.x;
    if (e < NEDGE) atomicAdd(&cnt[col[e]], 1);
}

// ---------------- scan (block-local) + top-level block sums ----------------
__global__ __launch_bounds__(SCAN_BLK) void k_scan_block(const int* __restrict__ cnt,
                                                         int* __restrict__ off,
                                                         int* __restrict__ bsum) {
    __shared__ int A[SCAN_BLK], B[SCAN_BLK];
    int tid = threadIdx.x;
    int i = blockIdx.x * SCAN_BLK + tid;
    int v = (i < NTGT) ? cnt[i] : 0;
    A[tid] = v;
    int* src = A; int* dst = B;
    for (int d = 1; d < SCAN_BLK; d <<= 1) {
        __syncthreads();
        dst[tid] = src[tid] + ((tid >= d) ? src[tid - d] : 0);
        int* t = src; src = dst; dst = t;
    }
    __syncthreads();
    if (i < NTGT) off[i] = src[tid] - v;  // block-local exclusive
    if (tid == SCAN_BLK - 1) bsum[blockIdx.x] = src[tid];
}

__global__ __launch_bounds__(128) void k_scan_top(int* __restrict__ bsum,
                                                  int* __restrict__ bscan) {
    __shared__ int A[128], B[128];
    int tid = threadIdx.x;
    int v = (tid < SCAN_NB) ? bsum[tid] : 0;
    A[tid] = v;
    int* src = A; int* dst = B;
    for (int d = 1; d < 128; d <<= 1) {
        __syncthreads();
        dst[tid] = src[tid] + ((tid >= d) ? src[tid - d] : 0);
        int* t = src; src = dst; dst = t;
    }
    __syncthreads();
    if (tid < SCAN_NB) bscan[tid] = src[tid] - v;
}

// ---------------- bucket edges by target; off[c] becomes end-offset -------
__global__ void k_build(const int* __restrict__ row, const int* __restrict__ col,
                        int* __restrict__ off, const int* __restrict__ bscan,
                        int* __restrict__ csr) {
    int e = blockIdx.x * blockDim.x + threadIdx.x;
    if (e < NEDGE) {
        int c = col[e];
        int pos = bscan[c >> 9] + atomicAdd(&off[c], 1);
        csr[pos] = row[e];
    }
}

// ---------------- h = x @ W via bf16 MFMA; B staged in LDS, 2 chunks/blk --
// block = 256 thr (4 waves), 64 rows/chunk. Wave w -> rows base+w*16..+15.
// 8 n-tiles of 16 cols; K=128 in 4 MFMA steps of 32.
__global__ __launch_bounds__(256) void k_gemm(const float* __restrict__ xsrc,
                                              const float* __restrict__ xtgt,
                                              const unsigned short* __restrict__ Wt,
                                              unsigned short* __restrict__ h,
                                              float* __restrict__ out) {
    __shared__ unsigned short Bs[128 * WPAD];  // 34 KB: [n][k] bf16, padded
    __shared__ unsigned short Hs[64 * 128];    // 16 KB epilogue staging

    const int tid = threadIdx.x;

    // stage Wt -> LDS once per block (coalesced uint4, 8 ushorts/thread/iter)
    for (int idx = tid; idx < 2048; idx += 256) {
        int n = idx >> 4, c8 = idx & 15;
        uint4 v = *(const uint4*)(Wt + n * DIM + c8 * 8);
        *(uint4*)&Bs[n * WPAD + c8 * 8] = v;
    }
    __syncthreads();

    const int wave = tid >> 6, lane = tid & 63;
    const int nl = lane & 15, quad = lane >> 4;

    for (int ch = 0; ch < CHUNKS_PER_BLK; ++ch) {
        const int base = (blockIdx.x * CHUNKS_PER_BLK + ch) * 64;
        if (base >= NTOT) break;  // block-uniform

        int m = base + wave * 16 + nl;
        int mc = (m < NTOT) ? m : (NTOT - 1);  // clamp tail loads
        const float* xrow = (mc < NSRC) ? (xsrc + (size_t)mc * DIM)
                                        : (xtgt + (size_t)(mc - NSRC) * DIM);

        float4v acc[8];
#pragma unroll
        for (int t = 0; t < 8; ++t) acc[t] = (float4v){0.f, 0.f, 0.f, 0.f};

#pragma unroll
        for (int s = 0; s < 4; ++s) {
            int k0 = s * 32 + quad * 8;
            float4 a0 = *(const float4*)(xrow + k0);
            float4 a1 = *(const float4*)(xrow + k0 + 4);
            short8 af;
            af[0] = (short)f2bf(a0.x); af[1] = (short)f2bf(a0.y);
            af[2] = (short)f2bf(a0.z); af[3] = (short)f2bf(a0.w);
            af[4] = (short)f2bf(a1.x); af[5] = (short)f2bf(a1.y);
            af[6] = (short)f2bf(a1.z); af[7] = (short)f2bf(a1.w);
#pragma unroll
            for (int t = 0; t < 8; ++t) {
                short8 bf = *(const short8*)&Bs[(t * 16 + nl) * WPAD + k0];
                acc[t] = __builtin_amdgcn_mfma_f32_16x16x32_bf16(af, bf, acc[t], 0, 0, 0);
            }
        }

        if (ch) __syncthreads();  // Hs readout of prev chunk complete
        // C/D layout: col = lane&15 (within n-tile), row = quad*4 + reg
#pragma unroll
        for (int t = 0; t < 8; ++t)
#pragma unroll
            for (int r = 0; r < 4; ++r)
                Hs[(wave * 16 + quad * 4 + r) * 128 + t * 16 + nl] = f2bf(acc[t][r]);
        __syncthreads();

        // coalesced readout: each thread 4 chunks of 8 bf16
#pragma unroll
        for (int j = 0; j < 4; ++j) {
            int off_us = tid * 8 + j * 2048;  // ushort index into Hs
            int g = base + (off_us >> 7);
            int colc = off_us & 127;
            if (g < NTOT) {
                uint4 v = *(const uint4*)&Hs[off_us];
                *(uint4*)(h + (size_t)g * DIM + colc) = v;
                if (g < NSRC) {  // source nodes: deg=1 -> out = relu(h)
                    unsigned pk[4] = {v.x, v.y, v.z, v.w};
                    float4 o0, o1;
                    o0.x = fmaxf(bf2f(pk[0] & 0xffff), 0.f);
                    o0.y = fmaxf(bf2f(pk[0] >> 16), 0.f);
                    o0.z = fmaxf(bf2f(pk[1] & 0xffff), 0.f);
                    o0.w = fmaxf(bf2f(pk[1] >> 16), 0.f);
                    o1.x = fmaxf(bf2f(pk[2] & 0xffff), 0.f);
                    o1.y = fmaxf(bf2f(pk[2] >> 16), 0.f);
                    o1.z = fmaxf(bf2f(pk[3] & 0xffff), 0.f);
                    o1.w = fmaxf(bf2f(pk[3] >> 16), 0.f);
                    float* op = out + (size_t)g * DIM + colc;
                    *(float4*)op = o0;
                    *(float4*)(op + 4) = o1;
                }
            }
        }
    }
}

// ---------------- per-target gather-reduce (bf16 h, 2 edges/iter) ---------
// one wave per target; half-wave (32 lanes) per edge, uint2 (4 bf16)/lane
// after k_build, off[c] = local_start + cnt[c]; global start = bscan+off-n
__global__ __launch_bounds__(256) void k_agg(const int* __restrict__ off,
                                             const int* __restrict__ cnt,
                                             const int* __restrict__ bscan,
                                             const int* __restrict__ csr,
                                             const unsigned short* __restrict__ h,
                                             float* __restrict__ out) {
    int w = threadIdx.x >> 6;
    int lane = threadIdx.x & 63;
    int c = blockIdx.x * 4 + w;
    if (c >= NTGT) return;

    int n = cnt[c];
    int s0 = off[c] + bscan[c >> 9] - n;
    int half = lane >> 5;   // 0: even edges, 1: odd edges
    int hl = lane & 31;     // covers cols 4*hl .. 4*hl+3

    float4 sum = make_float4(0.f, 0.f, 0.f, 0.f);
    int j = 0;
    while (j < n) {
        int nb = (n - j < 64) ? (n - j) : 64;
        int v = (lane < nb) ? csr[s0 + j + lane] : 0;
        int npair = nb & ~1;
        int kk = 0;
#pragma unroll 8
        for (; kk < npair; kk += 2) {
            int r = __shfl(v, kk + half, 64);
            uint2 d = *(const uint2*)(h + (size_t)r * DIM + hl * 4);
            sum.x += bf2f(d.x & 0xffff); sum.y += bf2f(d.x >> 16);
            sum.z += bf2f(d.y & 0xffff); sum.w += bf2f(d.y >> 16);
        }
        if (kk < nb) {  // odd leftover: half 0 only
            int r = __shfl(v, kk, 64);
            if (half == 0) {
                uint2 d = *(const uint2*)(h + (size_t)r * DIM + hl * 4);
                sum.x += bf2f(d.x & 0xffff); sum.y += bf2f(d.x >> 16);
                sum.z += bf2f(d.y & 0xffff); sum.w += bf2f(d.y >> 16);
            }
        }
        j += nb;
    }

    // combine halves: lane l (<32) needs + lane l+32
    float4 tot;
    tot.x = sum.x + __shfl(sum.x, lane ^ 32, 64);
    tot.y = sum.y + __shfl(sum.y, lane ^ 32, 64);
    tot.z = sum.z + __shfl(sum.z, lane ^ 32, 64);
    tot.w = sum.w + __shfl(sum.w, lane ^ 32, 64);

    if (half == 0) {
        float di = rsqrtf(1.0f + (float)n);
        float dd = di * di;
        uint2 dh = *(const uint2*)(h + (size_t)(NSRC + c) * DIM + hl * 4);
        float4 o;
        o.x = fmaxf(di * tot.x + dd * bf2f(dh.x & 0xffff), 0.f);
        o.y = fmaxf(di * tot.y + dd * bf2f(dh.x >> 16), 0.f);
        o.z = fmaxf(di * tot.z + dd * bf2f(dh.y & 0xffff), 0.f);
        o.w = fmaxf(di * tot.w + dd * bf2f(dh.y >> 16), 0.f);
        *(float4*)(out + (size_t)(NSRC + c) * DIM + hl * 4) = o;
    }
}

extern "C" void kernel_launch(void* const* d_in, const int* in_sizes, int n_in,
                              void* d_out, int out_size, void* d_ws, size_t ws_size,
                              hipStream_t stream) {
    const int* ei     = (const int*)d_in[0];    // [2, E] int32
    const float* xsrc = (const float*)d_in[1];  // [NSRC, 128]
    const float* xtgt = (const float*)d_in[2];  // [NTGT, 128]
    const float* W    = (const float*)d_in[3];  // [128, 128]
    float* out = (float*)d_out;                 // [NTOT, 128]

    const int* row = ei;
    const int* col = ei + NEDGE;

    char* ws = (char*)d_ws;
    unsigned short* h  = (unsigned short*)ws;  ws += (size_t)NTOT * DIM * 2;  // 25.6 MB
    unsigned short* Wt = (unsigned short*)ws;  ws += DIM * DIM * 2;           // 32 KB
    int* cnt    = (int*)ws;                    ws += NTGT * 4;
    int* off    = (int*)ws;                    ws += NTGT * 4;
    int* bsum   = (int*)ws;                    ws += 512;
    int* bscan  = (int*)ws;                    ws += 512;
    int* csr    = (int*)ws;                    ws += (size_t)NEDGE * 4;       // 3.2 MB

    k_prep<<<(NTGT + 255) / 256, 256, 0, stream>>>(W, Wt, cnt);
    k_hist<<<(NEDGE + 255) / 256, 256, 0, stream>>>(col, cnt);
    k_scan_block<<<SCAN_NB, SCAN_BLK, 0, stream>>>(cnt, off, bsum);
    k_scan_top<<<1, 128, 0, stream>>>(bsum, bscan);
    k_build<<<(NEDGE + 255) / 256, 256, 0, stream>>>(row, col, off, bscan, csr);
    k_gemm<<<GEMM_GRID, 256, 0, stream>>>(xsrc, xtgt, Wt, h, out);
    k_agg<<<(NTGT + 3) / 4, 256, 0, stream>>>(off, cnt, bscan, csr, h, out);
}

// Round 6
// 196.232 us; speedup vs baseline: 1.3560x; 1.2675x over previous
//
#include <hip/hip_runtime.h>
#include <math.h>

#define NSRC 50000
#define NTGT 50000
#define NTOT 100000
#define NEDGE 800000
#define DIM 128
#define WPAD 136        // Wt LDS row pitch (ushorts): 2-way bank alias = free
#define CHUNKS_PER_BLK 2
#define GEMM_GRID 782   // ceil(1563 / 2)

#define NBUCK 196       // coarse buckets of 256 targets (49999>>8 = 195)
#define PBLK 98         // partition blocks
#define EPB 8192        // edges per partition block (98*8192 = 802816 >= 800000)
#define SCAN_N (NBUCK * PBLK)   // 19208
#define SCAN_PER_THR 19         // 1024*19 = 19456 >= 19208
#define BCAP 6144       // max edges per bucket (mean 4082, +32 sigma)

typedef __attribute__((ext_vector_type(8))) short short8;
typedef __attribute__((ext_vector_type(4))) float float4v;

__device__ __forceinline__ unsigned short f2bf(float f) {
    unsigned u = __float_as_uint(f);
    unsigned r = (u + 0x7FFFu + ((u >> 16) & 1u)) >> 16;  // RNE
    return (unsigned short)r;
}
__device__ __forceinline__ float bf2f(unsigned us) {
    return __uint_as_float(us << 16);
}

// ---------------- prep: W -> Wt (bf16, transposed) ----------------
__global__ void k_prep(const float* __restrict__ W, unsigned short* __restrict__ Wt) {
    int i = blockIdx.x * blockDim.x + threadIdx.x;
    if (i < DIM * DIM) {
        int k = i >> 7, n = i & 127;
        Wt[n * DIM + k] = f2bf(W[i]);
    }
}

// ---------------- pass A: per-(bucket, block) counts ----------------
__global__ __launch_bounds__(1024) void k_count(const int* __restrict__ col,
                                                int* __restrict__ H) {
    __shared__ int hist[NBUCK];
    int tid = threadIdx.x;
    if (tid < NBUCK) hist[tid] = 0;
    __syncthreads();
    int e0 = blockIdx.x * EPB;
    for (int i = tid; i < EPB; i += 1024) {
        int e = e0 + i;
        if (e < NEDGE) atomicAdd(&hist[col[e] >> 8], 1);
    }
    __syncthreads();
    if (tid < NBUCK) H[tid * PBLK + blockIdx.x] = hist[tid];
}

// ---------------- pass B: exclusive scan of H[19208] in place ----------------
__global__ __launch_bounds__(1024) void k_scan(int* __restrict__ H) {
    __shared__ int P[1024], Q[1024];
    int tid = threadIdx.x;
    int base = tid * SCAN_PER_THR;
    int v[SCAN_PER_THR];
    int s = 0;
#pragma unroll
    for (int i = 0; i < SCAN_PER_THR; ++i) {
        int idx = base + i;
        int x = (idx < SCAN_N) ? H[idx] : 0;
        v[i] = s;  // thread-local exclusive
        s += x;
    }
    P[tid] = s;
    int* src = P; int* dst = Q;
    for (int d = 1; d < 1024; d <<= 1) {
        __syncthreads();
        dst[tid] = src[tid] + ((tid >= d) ? src[tid - d] : 0);
        int* t = src; src = dst; dst = t;
    }
    __syncthreads();
    int excl = src[tid] - s;  // block-level exclusive
#pragma unroll
    for (int i = 0; i < SCAN_PER_THR; ++i) {
        int idx = base + i;
        if (idx < SCAN_N) H[idx] = excl + v[i];
    }
}

// ---------------- pass C: partition edges into coarse buckets ----------------
// packed entry: row (16 bits) | c_local (bits 16..23)
__global__ __launch_bounds__(1024) void k_part(const int* __restrict__ row,
                                               const int* __restrict__ col,
                                               const int* __restrict__ S,
                                               unsigned* __restrict__ part) {
    __shared__ int cur[NBUCK];
    int tid = threadIdx.x;
    if (tid < NBUCK) cur[tid] = S[tid * PBLK + blockIdx.x];
    __syncthreads();
    int e0 = blockIdx.x * EPB;
    for (int i = tid; i < EPB; i += 1024) {
        int e = e0 + i;
        if (e < NEDGE) {
            int c = col[e];
            int q = c >> 8;
            int pos = atomicAdd(&cur[q], 1);
            part[pos] = (unsigned)row[e] | ((unsigned)(c & 255) << 16);
        }
    }
}

// ---------------- pass D: per-bucket local sort -> csr + tstart/tcnt -------
__global__ __launch_bounds__(1024) void k_bucket(const int* __restrict__ S,
                                                 const unsigned* __restrict__ part,
                                                 int* __restrict__ csr,
                                                 int* __restrict__ tstart,
                                                 int* __restrict__ tcnt) {
    __shared__ unsigned ebuf[BCAP];
    __shared__ unsigned short srt[BCAP];
    __shared__ int hist[256], bufA[256], bufB[256], cur[256];

    int q = blockIdx.x, tid = threadIdx.x;
    int base = S[q * PBLK];
    int end = (q == NBUCK - 1) ? NEDGE : S[(q + 1) * PBLK];
    int n = end - base;

    if (tid < 256) hist[tid] = 0;
    __syncthreads();
    for (int i = tid; i < n; i += 1024) {
        unsigned p = part[base + i];
        ebuf[i] = p;
        atomicAdd(&hist[p >> 16], 1);
    }
    __syncthreads();

    // exclusive scan of hist[256] (first 256 threads, double-buffered)
    if (tid < 256) bufA[tid] = hist[tid];
    int* src = bufA; int* dst = bufB;
    for (int d = 1; d < 256; d <<= 1) {
        __syncthreads();
        if (tid < 256) dst[tid] = src[tid] + ((tid >= d) ? src[tid - d] : 0);
        int* t = src; src = dst; dst = t;
    }
    __syncthreads();
    if (tid < 256) {
        int excl = src[tid] - hist[tid];
        cur[tid] = excl;
        int c = q * 256 + tid;
        if (c < NTGT) {
            tstart[c] = base + excl;
            tcnt[c] = hist[tid];
        }
    }
    __syncthreads();

    for (int i = tid; i < n; i += 1024) {
        unsigned p = ebuf[i];
        int pos = atomicAdd(&cur[p >> 16], 1);
        srt[pos] = (unsigned short)(p & 0xffffu);
    }
    __syncthreads();
    for (int i = tid; i < n; i += 1024) csr[base + i] = (int)srt[i];
}

// ---------------- h = x @ W via bf16 MFMA; B staged in LDS, 2 chunks/blk --
__global__ __launch_bounds__(256) void k_gemm(const float* __restrict__ xsrc,
                                              const float* __restrict__ xtgt,
                                              const unsigned short* __restrict__ Wt,
                                              unsigned short* __restrict__ h,
                                              float* __restrict__ out) {
    __shared__ unsigned short Bs[128 * WPAD];  // 34 KB: [n][k] bf16, padded
    __shared__ unsigned short Hs[64 * 128];    // 16 KB epilogue staging

    const int tid = threadIdx.x;

    for (int idx = tid; idx < 2048; idx += 256) {
        int n = idx >> 4, c8 = idx & 15;
        uint4 v = *(const uint4*)(Wt + n * DIM + c8 * 8);
        *(uint4*)&Bs[n * WPAD + c8 * 8] = v;
    }
    __syncthreads();

    const int wave = tid >> 6, lane = tid & 63;
    const int nl = lane & 15, quad = lane >> 4;

    for (int ch = 0; ch < CHUNKS_PER_BLK; ++ch) {
        const int base = (blockIdx.x * CHUNKS_PER_BLK + ch) * 64;
        if (base >= NTOT) break;  // block-uniform

        int m = base + wave * 16 + nl;
        int mc = (m < NTOT) ? m : (NTOT - 1);
        const float* xrow = (mc < NSRC) ? (xsrc + (size_t)mc * DIM)
                                        : (xtgt + (size_t)(mc - NSRC) * DIM);

        float4v acc[8];
#pragma unroll
        for (int t = 0; t < 8; ++t) acc[t] = (float4v){0.f, 0.f, 0.f, 0.f};

#pragma unroll
        for (int s = 0; s < 4; ++s) {
            int k0 = s * 32 + quad * 8;
            float4 a0 = *(const float4*)(xrow + k0);
            float4 a1 = *(const float4*)(xrow + k0 + 4);
            short8 af;
            af[0] = (short)f2bf(a0.x); af[1] = (short)f2bf(a0.y);
            af[2] = (short)f2bf(a0.z); af[3] = (short)f2bf(a0.w);
            af[4] = (short)f2bf(a1.x); af[5] = (short)f2bf(a1.y);
            af[6] = (short)f2bf(a1.z); af[7] = (short)f2bf(a1.w);
#pragma unroll
            for (int t = 0; t < 8; ++t) {
                short8 bf = *(const short8*)&Bs[(t * 16 + nl) * WPAD + k0];
                acc[t] = __builtin_amdgcn_mfma_f32_16x16x32_bf16(af, bf, acc[t], 0, 0, 0);
            }
        }

        if (ch) __syncthreads();
#pragma unroll
        for (int t = 0; t < 8; ++t)
#pragma unroll
            for (int r = 0; r < 4; ++r)
                Hs[(wave * 16 + quad * 4 + r) * 128 + t * 16 + nl] = f2bf(acc[t][r]);
        __syncthreads();

#pragma unroll
        for (int j = 0; j < 4; ++j) {
            int off_us = tid * 8 + j * 2048;
            int g = base + (off_us >> 7);
            int colc = off_us & 127;
            if (g < NTOT) {
                uint4 v = *(const uint4*)&Hs[off_us];
                *(uint4*)(h + (size_t)g * DIM + colc) = v;
                if (g < NSRC) {  // source nodes: deg=1 -> out = relu(h)
                    unsigned pk[4] = {v.x, v.y, v.z, v.w};
                    float4 o0, o1;
                    o0.x = fmaxf(bf2f(pk[0] & 0xffff), 0.f);
                    o0.y = fmaxf(bf2f(pk[0] >> 16), 0.f);
                    o0.z = fmaxf(bf2f(pk[1] & 0xffff), 0.f);
                    o0.w = fmaxf(bf2f(pk[1] >> 16), 0.f);
                    o1.x = fmaxf(bf2f(pk[2] & 0xffff), 0.f);
                    o1.y = fmaxf(bf2f(pk[2] >> 16), 0.f);
                    o1.z = fmaxf(bf2f(pk[3] & 0xffff), 0.f);
                    o1.w = fmaxf(bf2f(pk[3] >> 16), 0.f);
                    float* op = out + (size_t)g * DIM + colc;
                    *(float4*)op = o0;
                    *(float4*)(op + 4) = o1;
                }
            }
        }
    }
}

// ---------------- per-target gather-reduce (bf16 h, 2 edges/iter) ---------
__global__ __launch_bounds__(256) void k_agg(const int* __restrict__ tstart,
                                             const int* __restrict__ tcnt,
                                             const int* __restrict__ csr,
                                             const unsigned short* __restrict__ h,
                                             float* __restrict__ out) {
    int w = threadIdx.x >> 6;
    int lane = threadIdx.x & 63;
    int c = blockIdx.x * 4 + w;
    if (c >= NTGT) return;

    int n = tcnt[c];
    int s0 = tstart[c];
    int half = lane >> 5;   // 0: even edges, 1: odd edges
    int hl = lane & 31;     // covers cols 4*hl .. 4*hl+3

    float4 sum = make_float4(0.f, 0.f, 0.f, 0.f);
    int j = 0;
    while (j < n) {
        int nb = (n - j < 64) ? (n - j) : 64;
        int v = (lane < nb) ? csr[s0 + j + lane] : 0;
        int npair = nb & ~1;
        int kk = 0;
#pragma unroll 8
        for (; kk < npair; kk += 2) {
            int r = __shfl(v, kk + half, 64);
            uint2 d = *(const uint2*)(h + (size_t)r * DIM + hl * 4);
            sum.x += bf2f(d.x & 0xffff); sum.y += bf2f(d.x >> 16);
            sum.z += bf2f(d.y & 0xffff); sum.w += bf2f(d.y >> 16);
        }
        if (kk < nb) {  // odd leftover: half 0 only
            int r = __shfl(v, kk, 64);
            if (half == 0) {
                uint2 d = *(const uint2*)(h + (size_t)r * DIM + hl * 4);
                sum.x += bf2f(d.x & 0xffff); sum.y += bf2f(d.x >> 16);
                sum.z += bf2f(d.y & 0xffff); sum.w += bf2f(d.y >> 16);
            }
        }
        j += nb;
    }

    float4 tot;
    tot.x = sum.x + __shfl(sum.x, lane ^ 32, 64);
    tot.y = sum.y + __shfl(sum.y, lane ^ 32, 64);
    tot.z = sum.z + __shfl(sum.z, lane ^ 32, 64);
    tot.w = sum.w + __shfl(sum.w, lane ^ 32, 64);

    if (half == 0) {
        float di = rsqrtf(1.0f + (float)n);
        float dd = di * di;
        uint2 dh = *(const uint2*)(h + (size_t)(NSRC + c) * DIM + hl * 4);
        float4 o;
        o.x = fmaxf(di * tot.x + dd * bf2f(dh.x & 0xffff), 0.f);
        o.y = fmaxf(di * tot.y + dd * bf2f(dh.x >> 16), 0.f);
        o.z = fmaxf(di * tot.z + dd * bf2f(dh.y & 0xffff), 0.f);
        o.w = fmaxf(di * tot.w + dd * bf2f(dh.y >> 16), 0.f);
        *(float4*)(out + (size_t)(NSRC + c) * DIM + hl * 4) = o;
    }
}

extern "C" void kernel_launch(void* const* d_in, const int* in_sizes, int n_in,
                              void* d_out, int out_size, void* d_ws, size_t ws_size,
                              hipStream_t stream) {
    const int* ei     = (const int*)d_in[0];    // [2, E] int32
    const float* xsrc = (const float*)d_in[1];  // [NSRC, 128]
    const float* xtgt = (const float*)d_in[2];  // [NTGT, 128]
    const float* W    = (const float*)d_in[3];  // [128, 128]
    float* out = (float*)d_out;                 // [NTOT, 128]

    const int* row = ei;
    const int* col = ei + NEDGE;

    char* ws = (char*)d_ws;
    unsigned short* h  = (unsigned short*)ws;  ws += (size_t)NTOT * DIM * 2;  // 25.6 MB
    unsigned short* Wt = (unsigned short*)ws;  ws += DIM * DIM * 2;           // 32 KB
    unsigned* part = (unsigned*)ws;            ws += (size_t)NEDGE * 4;       // 3.2 MB
    int* csr    = (int*)ws;                    ws += (size_t)NEDGE * 4;       // 3.2 MB
    int* S      = (int*)ws;                    ws += 19456 * 4;               // 78 KB
    int* tstart = (int*)ws;                    ws += NTGT * 4;
    int* tcnt   = (int*)ws;                    ws += NTGT * 4;

    k_prep<<<(DIM * DIM + 255) / 256, 256, 0, stream>>>(W, Wt);
    k_count<<<PBLK, 1024, 0, stream>>>(col, S);
    k_scan<<<1, 1024, 0, stream>>>(S);
    k_part<<<PBLK, 1024, 0, stream>>>(row, col, S, part);
    k_bucket<<<NBUCK, 1024, 0, stream>>>(S, part, csr, tstart, tcnt);
    k_gemm<<<GEMM_GRID, 256, 0, stream>>>(xsrc, xtgt, Wt, h, out);
    k_agg<<<(NTGT + 3) / 4, 256, 0, stream>>>(tstart, tcnt, csr, h, out);
}

// Round 8
// 171.266 us; speedup vs baseline: 1.5537x; 1.1458x over previous
//
#include <hip/hip_runtime.h>
#include <math.h>

#define NSRC 50000
#define NTGT 50000
#define NTOT 100000
#define NEDGE 800000
#define DIM 128
#define WPAD 136        // Wt LDS row pitch (ushorts): 2-way bank alias = free
#define CHUNKS_PER_BLK 2
#define GEMM_GRID 782   // ceil(1563 / 2)

#define NBUCK 196       // coarse buckets of 256 targets (49999>>8 = 195)
#define PBLK 98         // partition blocks
#define EPB 8192        // edges per partition block (98*8192 >= 800000)
#define BCAP 6144       // max edges per bucket (mean 4096, +32 sigma)

typedef __attribute__((ext_vector_type(8))) short short8;
typedef __attribute__((ext_vector_type(4))) float float4v;

__device__ __forceinline__ unsigned short f2bf(float f) {
    unsigned u = __float_as_uint(f);
    unsigned r = (u + 0x7FFFu + ((u >> 16) & 1u)) >> 16;  // RNE
    return (unsigned short)r;
}
__device__ __forceinline__ float bf2f(unsigned us) {
    return __uint_as_float(us << 16);
}

// ---------------- prep: W -> Wt (bf16, transposed) + zero bcnt ------------
__global__ void k_prep(const float* __restrict__ W, unsigned short* __restrict__ Wt,
                       int* __restrict__ bcnt) {
    int i = blockIdx.x * blockDim.x + threadIdx.x;
    if (i < NBUCK) bcnt[i] = 0;
    if (i < DIM * DIM) {
        int k = i >> 7, n = i & 127;
        Wt[n * DIM + k] = f2bf(W[i]);
    }
}

// ---------------- fused count + run-reserve + partition ----------------
// packed entry: row (16 bits) | c_local (bits 16..23)
__global__ __launch_bounds__(1024) void k_part2(const int* __restrict__ row,
                                                const int* __restrict__ col,
                                                int* __restrict__ bcnt,
                                                unsigned* __restrict__ part) {
    __shared__ int hist[NBUCK], runbase[NBUCK], cur[NBUCK];
    int tid = threadIdx.x;
    if (tid < NBUCK) hist[tid] = 0;
    __syncthreads();
    int e0 = blockIdx.x * EPB;
    int eend = (e0 + EPB < NEDGE) ? e0 + EPB : NEDGE;
    for (int e = e0 + tid; e < eend; e += 1024)
        atomicAdd(&hist[col[e] >> 8], 1);
    __syncthreads();
    if (tid < NBUCK) {
        runbase[tid] = atomicAdd(&bcnt[tid], hist[tid]);  // reserve run
        cur[tid] = 0;
    }
    __syncthreads();
    for (int e = e0 + tid; e < eend; e += 1024) {
        int c = col[e];
        int q = c >> 8;
        int pos = runbase[q] + atomicAdd(&cur[q], 1);
        part[q * BCAP + pos] = (unsigned)row[e] | ((unsigned)(c & 255) << 16);
    }
}

// ---------------- per-bucket local sort -> csr (ushort) + tstart/tcnt -----
__global__ __launch_bounds__(1024) void k_bucket(const int* __restrict__ bcnt,
                                                 const unsigned* __restrict__ part,
                                                 unsigned short* __restrict__ csr,
                                                 int* __restrict__ tstart,
                                                 int* __restrict__ tcnt) {
    __shared__ unsigned ebuf[BCAP];
    __shared__ unsigned short srt[BCAP];
    __shared__ int hist[256], bufA[256], bufB[256], cur[256];

    int q = blockIdx.x, tid = threadIdx.x;
    int n = bcnt[q];
    int base = q * BCAP;

    if (tid < 256) hist[tid] = 0;
    __syncthreads();
    for (int i = tid; i < n; i += 1024) {
        unsigned p = part[base + i];
        ebuf[i] = p;
        atomicAdd(&hist[p >> 16], 1);
    }
    __syncthreads();

    // exclusive scan of hist[256] (first 256 threads, double-buffered)
    if (tid < 256) bufA[tid] = hist[tid];
    int* src = bufA; int* dst = bufB;
    for (int d = 1; d < 256; d <<= 1) {
        __syncthreads();
        if (tid < 256) dst[tid] = src[tid] + ((tid >= d) ? src[tid - d] : 0);
        int* t = src; src = dst; dst = t;
    }
    __syncthreads();
    if (tid < 256) {
        int excl = src[tid] - hist[tid];
        cur[tid] = excl;
        int c = q * 256 + tid;
        if (c < NTGT) {
            tstart[c] = base + excl;
            tcnt[c] = hist[tid];
        }
    }
    __syncthreads();

    for (int i = tid; i < n; i += 1024) {
        unsigned p = ebuf[i];
        int pos = atomicAdd(&cur[p >> 16], 1);
        srt[pos] = (unsigned short)(p & 0xffffu);
    }
    __syncthreads();
    // coalesced writeout, 2 ushorts per store (base is 4B-aligned: BCAP even)
    int m = (n + 1) >> 1;
    unsigned* dst32 = (unsigned*)(csr + base);
    for (int i = tid; i < m; i += 1024) dst32[i] = ((unsigned*)srt)[i];
}

// ---------------- h = x @ W via bf16 MFMA; B staged in LDS, 2 chunks/blk --
__global__ __launch_bounds__(256) void k_gemm(const float* __restrict__ xsrc,
                                              const float* __restrict__ xtgt,
                                              const unsigned short* __restrict__ Wt,
                                              unsigned short* __restrict__ h,
                                              float* __restrict__ out) {
    __shared__ unsigned short Bs[128 * WPAD];  // 34 KB: [n][k] bf16, padded
    __shared__ unsigned short Hs[64 * 128];    // 16 KB epilogue staging

    const int tid = threadIdx.x;

    for (int idx = tid; idx < 2048; idx += 256) {
        int n = idx >> 4, c8 = idx & 15;
        uint4 v = *(const uint4*)(Wt + n * DIM + c8 * 8);
        *(uint4*)&Bs[n * WPAD + c8 * 8] = v;
    }
    __syncthreads();

    const int wave = tid >> 6, lane = tid & 63;
    const int nl = lane & 15, quad = lane >> 4;

    for (int ch = 0; ch < CHUNKS_PER_BLK; ++ch) {
        const int base = (blockIdx.x * CHUNKS_PER_BLK + ch) * 64;
        if (base >= NTOT) break;  // block-uniform

        int m = base + wave * 16 + nl;
        int mc = (m < NTOT) ? m : (NTOT - 1);
        const float* xrow = (mc < NSRC) ? (xsrc + (size_t)mc * DIM)
                                        : (xtgt + (size_t)(mc - NSRC) * DIM);

        float4v acc[8];
#pragma unroll
        for (int t = 0; t < 8; ++t) acc[t] = (float4v){0.f, 0.f, 0.f, 0.f};

#pragma unroll
        for (int s = 0; s < 4; ++s) {
            int k0 = s * 32 + quad * 8;
            float4 a0 = *(const float4*)(xrow + k0);
            float4 a1 = *(const float4*)(xrow + k0 + 4);
            short8 af;
            af[0] = (short)f2bf(a0.x); af[1] = (short)f2bf(a0.y);
            af[2] = (short)f2bf(a0.z); af[3] = (short)f2bf(a0.w);
            af[4] = (short)f2bf(a1.x); af[5] = (short)f2bf(a1.y);
            af[6] = (short)f2bf(a1.z); af[7] = (short)f2bf(a1.w);
#pragma unroll
            for (int t = 0; t < 8; ++t) {
                short8 bf = *(const short8*)&Bs[(t * 16 + nl) * WPAD + k0];
                acc[t] = __builtin_amdgcn_mfma_f32_16x16x32_bf16(af, bf, acc[t], 0, 0, 0);
            }
        }

        if (ch) __syncthreads();
#pragma unroll
        for (int t = 0; t < 8; ++t)
#pragma unroll
            for (int r = 0; r < 4; ++r)
                Hs[(wave * 16 + quad * 4 + r) * 128 + t * 16 + nl] = f2bf(acc[t][r]);
        __syncthreads();

#pragma unroll
        for (int j = 0; j < 4; ++j) {
            int off_us = tid * 8 + j * 2048;
            int g = base + (off_us >> 7);
            int colc = off_us & 127;
            if (g < NTOT) {
                uint4 v = *(const uint4*)&Hs[off_us];
                *(uint4*)(h + (size_t)g * DIM + colc) = v;
                if (g < NSRC) {  // source nodes: deg=1 -> out = relu(h)
                    unsigned pk[4] = {v.x, v.y, v.z, v.w};
                    float4 o0, o1;
                    o0.x = fmaxf(bf2f(pk[0] & 0xffff), 0.f);
                    o0.y = fmaxf(bf2f(pk[0] >> 16), 0.f);
                    o0.z = fmaxf(bf2f(pk[1] & 0xffff), 0.f);
                    o0.w = fmaxf(bf2f(pk[1] >> 16), 0.f);
                    o1.x = fmaxf(bf2f(pk[2] & 0xffff), 0.f);
                    o1.y = fmaxf(bf2f(pk[2] >> 16), 0.f);
                    o1.z = fmaxf(bf2f(pk[3] & 0xffff), 0.f);
                    o1.w = fmaxf(bf2f(pk[3] >> 16), 0.f);
                    float* op = out + (size_t)g * DIM + colc;
                    *(float4*)op = o0;
                    *(float4*)(op + 4) = o1;
                }
            }
        }
    }
}

// ---------------- per-target gather-reduce (bf16 h, 4 edges/iter) ---------
// one wave per target; quarter-wave (16 lanes) per edge, uint4 (8 bf16)/lane
__global__ __launch_bounds__(256) void k_agg(const int* __restrict__ tstart,
                                             const int* __restrict__ tcnt,
                                             const unsigned short* __restrict__ csr,
                                             const unsigned short* __restrict__ h,
                                             float* __restrict__ out) {
    int w = threadIdx.x >> 6;
    int lane = threadIdx.x & 63;
    int c = blockIdx.x * 4 + w;
    if (c >= NTGT) return;

    int n = tcnt[c];
    int s0 = tstart[c];
    int q = lane >> 4;      // quarter: which edge of the group of 4
    int ql = lane & 15;     // covers cols 8*ql .. 8*ql+7

    float acc[8];
#pragma unroll
    for (int i = 0; i < 8; ++i) acc[i] = 0.f;

    int j = 0;
    while (j < n) {
        int nb = (n - j < 64) ? (n - j) : 64;
        int v = (lane < nb) ? (int)csr[s0 + j + lane] : 0;
        int n4 = nb & ~3;
        int kk = 0;
#pragma unroll 4
        for (; kk < n4; kk += 4) {
            int r = __shfl(v, kk + q, 64);
            uint4 d = *(const uint4*)(h + (size_t)r * DIM + ql * 8);
            acc[0] += bf2f(d.x & 0xffff); acc[1] += bf2f(d.x >> 16);
            acc[2] += bf2f(d.y & 0xffff); acc[3] += bf2f(d.y >> 16);
            acc[4] += bf2f(d.z & 0xffff); acc[5] += bf2f(d.z >> 16);
            acc[6] += bf2f(d.w & 0xffff); acc[7] += bf2f(d.w >> 16);
        }
        int rem = nb - kk;  // 0..3, wave-uniform
        if (rem) {
            // shfl must be executed by ALL lanes so source lanes kk..kk+rem-1
            // are active (divergent-source bpermute reads undefined data)
            int qq = (q < rem) ? q : 0;
            int r = __shfl(v, kk + qq, 64);
            if (q < rem) {
                uint4 d = *(const uint4*)(h + (size_t)r * DIM + ql * 8);
                acc[0] += bf2f(d.x & 0xffff); acc[1] += bf2f(d.x >> 16);
                acc[2] += bf2f(d.y & 0xffff); acc[3] += bf2f(d.y >> 16);
                acc[4] += bf2f(d.z & 0xffff); acc[5] += bf2f(d.z >> 16);
                acc[6] += bf2f(d.w & 0xffff); acc[7] += bf2f(d.w >> 16);
            }
        }
        j += nb;
    }

    // combine quarters: butterfly over lane bits 4,5
#pragma unroll
    for (int i = 0; i < 8; ++i) {
        acc[i] += __shfl_xor(acc[i], 16, 64);
        acc[i] += __shfl_xor(acc[i], 32, 64);
    }

    if (q == 0) {
        float di = rsqrtf(1.0f + (float)n);
        float dd = di * di;
        uint4 dh = *(const uint4*)(h + (size_t)(NSRC + c) * DIM + ql * 8);
        float4 o0, o1;
        o0.x = fmaxf(di * acc[0] + dd * bf2f(dh.x & 0xffff), 0.f);
        o0.y = fmaxf(di * acc[1] + dd * bf2f(dh.x >> 16), 0.f);
        o0.z = fmaxf(di * acc[2] + dd * bf2f(dh.y & 0xffff), 0.f);
        o0.w = fmaxf(di * acc[3] + dd * bf2f(dh.y >> 16), 0.f);
        o1.x = fmaxf(di * acc[4] + dd * bf2f(dh.z & 0xffff), 0.f);
        o1.y = fmaxf(di * acc[5] + dd * bf2f(dh.z >> 16), 0.f);
        o1.z = fmaxf(di * acc[6] + dd * bf2f(dh.w & 0xffff), 0.f);
        o1.w = fmaxf(di * acc[7] + dd * bf2f(dh.w >> 16), 0.f);
        float* op = out + (size_t)(NSRC + c) * DIM + ql * 8;
        *(float4*)op = o0;
        *(float4*)(op + 4) = o1;
    }
}

extern "C" void kernel_launch(void* const* d_in, const int* in_sizes, int n_in,
                              void* d_out, int out_size, void* d_ws, size_t ws_size,
                              hipStream_t stream) {
    const int* ei     = (const int*)d_in[0];    // [2, E] int32
    const float* xsrc = (const float*)d_in[1];  // [NSRC, 128]
    const float* xtgt = (const float*)d_in[2];  // [NTGT, 128]
    const float* W    = (const float*)d_in[3];  // [128, 128]
    float* out = (float*)d_out;                 // [NTOT, 128]

    const int* row = ei;
    const int* col = ei + NEDGE;

    char* ws = (char*)d_ws;
    unsigned short* h  = (unsigned short*)ws;  ws += (size_t)NTOT * DIM * 2;   // 25.6 MB
    unsigned short* Wt = (unsigned short*)ws;  ws += DIM * DIM * 2;            // 32 KB
    unsigned* part = (unsigned*)ws;            ws += (size_t)NBUCK * BCAP * 4; // 4.8 MB
    unsigned short* csr = (unsigned short*)ws; ws += (size_t)NBUCK * BCAP * 2; // 2.4 MB
    int* bcnt   = (int*)ws;                    ws += NBUCK * 4;
    int* tstart = (int*)ws;                    ws += NTGT * 4;
    int* tcnt   = (int*)ws;                    ws += NTGT * 4;

    k_prep<<<(DIM * DIM + 255) / 256, 256, 0, stream>>>(W, Wt, bcnt);
    k_part2<<<PBLK, 1024, 0, stream>>>(row, col, bcnt, part);
    k_bucket<<<NBUCK, 1024, 0, stream>>>(bcnt, part, csr, tstart, tcnt);
    k_gemm<<<GEMM_GRID, 256, 0, stream>>>(xsrc, xtgt, Wt, h, out);
    k_agg<<<(NTGT + 3) / 4, 256, 0, stream>>>(tstart, tcnt, csr, h, out);
}